// Round 11
// baseline (1822.629 us; speedup 1.0000x reference)
//
#include <hip/hip_runtime.h>
#include <cstdint>
#include <cstddef>

// Problem constants (fixed instance)
#define NN 100000
#define EE 320000
#define GG 2048
#define LL 8

// Workspace layout (float offsets).
#define O_Z    0ull                      // [N,256] fp32 z; h fp32 (in-place) after last apply
#define O_ZB   25600000ull               // [N,256] bf16 zin
#define O_HB   38400000ull               // [N,256] bf16 h
#define O_S1   51200000ull               // [G,256] S1
#define O_S2   (O_S1 + 524288ull)        // [G,256] S2
#define O_ABUF (O_S2 + 524288ull)        // [256]
#define O_BBUF (O_ABUF + 256ull)         // [256]
#define O_CNTI (O_BBUF + 256ull)         // [G] int
#define O_CNTF (O_CNTI + 2048ull)        // [G]
#define O_SCOR (O_CNTF + 2048ull)        // [N] scores (CSR cursor during setup)
#define O_WEFF (O_SCOR + 100000ull)      // [L,6,256]
#define O_BEFF (O_WEFF + 12288ull)       // [L,256]
#define O_DEG  (O_BEFF + 2048ull)        // [N] int
#define O_STRT (O_DEG + 100000ull)       // [N] int
#define O_BSUM (O_STRT + 100000ull)      // [512] int
#define O_CSR  (O_BSUM + 512ull)         // [E] x 16 B: 6 bf16 attrs + int src
#define O_W1P  (O_CSR + 1280000ull)      // 8 x 65536 bf16 = 262144 floats
#define O_W2P  (O_W1P + 262144ull)
#define O_ATP  (O_W2P + 262144ull)       // 32768 shorts = 16384 floats
#define O_GST  (O_ATP + 16384ull)        // [G] int gstart
#define O_NWP  (O_GST + 2048ull)         // node_w packed: 24576 shorts = 12288 floats
#define O_BNP  (O_NWP + 12288ull)        // bn partials: 2 x [64,256] = 32768 floats

typedef short s16x8 __attribute__((ext_vector_type(8)));
typedef float f32x4 __attribute__((ext_vector_type(4)));

__device__ inline float b2f(unsigned int lo16) {
  union { float f; unsigned int u; } x; x.u = lo16 << 16; return x.f;
}
__device__ inline unsigned short f2b(float f) {
  union { float f; unsigned int u; } x; x.f = f;
  unsigned int r = x.u + 0x7FFFu + ((x.u >> 16) & 1u);
  return (unsigned short)(r >> 16);
}
__device__ inline unsigned short f2b_lo(float v) {   // residual after bf16 hi
  unsigned short h = f2b(v);
  float hf = b2f((unsigned int)h);
  return f2b(v - hf);
}

__global__ __launch_bounds__(256) void k_zero(float* __restrict__ p, int n) {
  int i = blockIdx.x * 256 + threadIdx.x;
  int stride = gridDim.x * 256;
  for (; i < n; i += stride) p[i] = 0.0f;
}

__global__ __launch_bounds__(256) void k_count(const int* __restrict__ batch, int* __restrict__ cnti, int n) {
  int i = blockIdx.x * 256 + threadIdx.x;
  if (i < n) atomicAdd(&cnti[batch[i]], 1);
}

// single-block scan over G=2048 counts -> gstart (exclusive), cntf (clamped)
__global__ __launch_bounds__(256) void k_gscan(const int* __restrict__ cnti, int* __restrict__ gstart,
                                               float* __restrict__ cntf) {
  __shared__ int part[256];
  int t = threadIdx.x;
  int base = t * 8;
  int loc[8];
  int s = 0;
#pragma unroll
  for (int i = 0; i < 8; ++i) { loc[i] = s; s += cnti[base + i]; }
  part[t] = s;
  __syncthreads();
  for (int off = 1; off < 256; off <<= 1) {
    int u = (t >= off) ? part[t - off] : 0;
    __syncthreads();
    part[t] += u;
    __syncthreads();
  }
  int p = (t > 0) ? part[t - 1] : 0;
#pragma unroll
  for (int i = 0; i < 8; ++i) {
    gstart[base + i] = p + loc[i];
    float v = (float)cnti[base + i];
    cntf[base + i] = v > 1.0f ? v : 1.0f;
  }
}

// ---------------- CSR build ----------------
__global__ __launch_bounds__(256) void k_deg(const int* __restrict__ edst, int* __restrict__ deg, int ne) {
  int e = blockIdx.x * 256 + threadIdx.x;
  if (e < ne) atomicAdd(&deg[edst[e]], 1);
}

__global__ __launch_bounds__(256) void k_scan_part(const int* __restrict__ deg, int* __restrict__ start,
                                                   int* __restrict__ bsum, int n) {
  __shared__ int s[256];
  int i = blockIdx.x * 256 + threadIdx.x;
  int t = threadIdx.x;
  int v = (i < n) ? deg[i] : 0;
  s[t] = v;
  __syncthreads();
  for (int off = 1; off < 256; off <<= 1) {
    int u = (t >= off) ? s[t - off] : 0;
    __syncthreads();
    s[t] += u;
    __syncthreads();
  }
  if (i < n) start[i] = s[t] - v;
  if (t == 255) bsum[blockIdx.x] = s[255];
}

__global__ __launch_bounds__(512) void k_scan_top(int* __restrict__ bsum, int nb) {
  __shared__ int s[512];
  int t = threadIdx.x;
  int v = (t < nb) ? bsum[t] : 0;
  s[t] = v;
  __syncthreads();
  for (int off = 1; off < 512; off <<= 1) {
    int u = (t >= off) ? s[t - off] : 0;
    __syncthreads();
    s[t] += u;
    __syncthreads();
  }
  if (t < nb) bsum[t] = s[t] - v;
}

__global__ __launch_bounds__(256) void k_scan_add(int* __restrict__ start, const int* __restrict__ bsum,
                                                  int* __restrict__ cursor, int n) {
  int i = blockIdx.x * 256 + threadIdx.x;
  if (i < n) {
    int v = start[i] + bsum[blockIdx.x];
    start[i] = v;
    cursor[i] = v;
  }
}

// CSR entry: uint4 = {attr0|attr1<<16, attr2|attr3<<16, attr4|attr5<<16, src}
__global__ __launch_bounds__(256) void k_fill(const float* __restrict__ ea, const int* __restrict__ esrc,
                                              const int* __restrict__ edst, int* __restrict__ cursor,
                                              uint4* __restrict__ csr, int ne) {
  int e = blockIdx.x * 256 + threadIdx.x;
  if (e >= ne) return;
  int d = edst[e];
  int slot = atomicAdd(&cursor[d], 1);
  const float* ap = ea + (size_t)e * 6;
  uint4 v;
  v.x = (unsigned int)f2b(ap[0]) | ((unsigned int)f2b(ap[1]) << 16);
  v.y = (unsigned int)f2b(ap[2]) | ((unsigned int)f2b(ap[3]) << 16);
  v.z = (unsigned int)f2b(ap[4]) | ((unsigned int)f2b(ap[5]) << 16);
  v.w = (unsigned int)esrc[e];
  csr[slot] = v;
}

// W_eff[i] = edge_w @ conv_w[i]; b_eff[i] = edge_b @ conv_w[i] + conv_b[i]
__global__ __launch_bounds__(256) void k_wfuse(const float* __restrict__ edge_w, const float* __restrict__ edge_b,
                                               const float* __restrict__ conv_w, const float* __restrict__ conv_b,
                                               float* __restrict__ wef, float* __restrict__ bef) {
  __shared__ float ew[6 * 128 + 128];
  int i = blockIdx.x;
  int c = threadIdx.x;
  for (int idx = c; idx < 896; idx += 256)
    ew[idx] = idx < 768 ? edge_w[idx] : edge_b[idx - 768];
  __syncthreads();
  float acc[7] = {0.f, 0.f, 0.f, 0.f, 0.f, 0.f, 0.f};
  const float* cw = conv_w + (size_t)i * 32768 + c;
  for (int j = 0; j < 128; ++j) {
    float w = cw[(size_t)j * 256];
#pragma unroll
    for (int k = 0; k < 6; ++k) acc[k] = fmaf(ew[k * 128 + j], w, acc[k]);
    acc[6] = fmaf(ew[768 + j], w, acc[6]);
  }
#pragma unroll
  for (int k = 0; k < 6; ++k) wef[(size_t)i * 1536 + k * 256 + c] = acc[k];
  bef[(size_t)i * 256 + c] = acc[6] + conv_b[(size_t)i * 256 + c];
}

// pack ALL mlp/att weights to MFMA B-fragment order in one launch.
__global__ __launch_bounds__(256) void k_pack_all(const float* __restrict__ mw1, const float* __restrict__ mw2,
                                                  const float* __restrict__ aw1,
                                                  unsigned short* __restrict__ w1p,
                                                  unsigned short* __restrict__ w2p,
                                                  unsigned short* __restrict__ atp) {
  int id = blockIdx.x * 256 + threadIdx.x;   // 33*4096 total
  int cbu = id >> 12;
  if (cbu >= 33) return;
  int lid = id & 4095;
  int l = lid & 63;
  int ct = (lid >> 6) & 7;
  int ks = (lid >> 9) & 7;
  const float* B;
  unsigned short* Bp;
  int ldb, cb;
  if (cbu < 32) {
    int m = cbu >> 1;
    cb = cbu & 1;
    ldb = 256;
    if (m < 8) { B = mw1 + (size_t)m * 65536; Bp = w1p + (size_t)m * 65536; }
    else       { B = mw2 + (size_t)(m - 8) * 65536; Bp = w2p + (size_t)(m - 8) * 65536; }
  } else {
    B = aw1; Bp = atp; ldb = 128; cb = 0;
  }
  int n = cb * 128 + ct * 16 + (l & 15);
  int k0 = ks * 32 + (l >> 4) * 8;
  unsigned short* dst = Bp + (((size_t)cb << 12) | (size_t)lid) * 8;
#pragma unroll
  for (int j = 0; j < 8; ++j) dst[j] = f2b(B[(size_t)(k0 + j) * ldb + n]);
}

// pack node_w [48,256] -> bf16 K_eff=96 fragment order: [cb][ks3][ct][lane][8]
__global__ __launch_bounds__(256) void k_pack_node(const float* __restrict__ w,
                                                   unsigned short* __restrict__ Wp) {
  int id = blockIdx.x * 256 + threadIdx.x;   // 3072 total
  if (id >= 3072) return;
  int l = id & 63;
  int t = id >> 6;
  int ct = t & 7;
  int u = t >> 3;          // 0..5
  int ks = u % 3;
  int cb = u / 3;
  int n = cb * 128 + ct * 16 + (l & 15);
  unsigned short* dst = Wp + (size_t)id * 8;
#pragma unroll
  for (int j = 0; j < 8; ++j) {
    int kk = ks * 32 + ((l >> 4) << 3) + j;
    int ksrc = kk < 48 ? kk : kk - 48;
    dst[j] = f2b(w[(size_t)ksrc * 256 + n]);
  }
}

// hb = bf16(x @ node_w + node_b) via MFMA, x staged through LDS (coalesced global reads).
__global__ __launch_bounds__(256) void k_embed_mfma(const float* __restrict__ x,
                                                    const unsigned short* __restrict__ Wp,
                                                    const float* __restrict__ b,
                                                    unsigned short* __restrict__ hb, int M) {
  __shared__ float xs[64 * 50];                 // stride 50 to spread banks
  int tid = threadIdx.x;
  int row0g = blockIdx.x * 64;
  for (int idx = tid; idx < 3072; idx += 256) {
    int r = idx / 48, c = idx - r * 48;
    int gr = row0g + r; if (gr > M - 1) gr = M - 1;
    xs[r * 50 + c] = x[(size_t)gr * 48 + c];
  }
  __syncthreads();

  int l = tid & 63;
  int w = tid >> 6;
  int mloc = l & 15, q = l >> 4;
  int rowl0 = (w & 1) * 32;
  int colh = (w >> 1) * 128;

  f32x4 acc[2][8];
#pragma unroll
  for (int rt = 0; rt < 2; ++rt)
#pragma unroll
    for (int ct = 0; ct < 8; ++ct) acc[rt][ct] = (f32x4){0.f, 0.f, 0.f, 0.f};

  union { s16x8 v; unsigned short u[8]; } a[2][3];
#pragma unroll
  for (int rt = 0; rt < 2; ++rt) {
    const float* xr = xs + (rowl0 + rt * 16 + mloc) * 50;
    const float* p0 = xr + q * 8;
    const float* p1 = xr + (q < 2 ? 32 + q * 8 : (q - 2) * 8);
    const float* p2 = xr + 16 + q * 8;
#pragma unroll
    for (int j = 0; j < 8; ++j) {
      a[rt][0].u[j] = f2b(p0[j]);
      a[rt][1].u[j] = (q < 2) ? f2b(p1[j]) : f2b_lo(p1[j]);
      a[rt][2].u[j] = f2b_lo(p2[j]);
    }
  }

  const unsigned short* bp = Wp + (size_t)(colh >> 7) * 12288 + (size_t)l * 8;
#pragma unroll
  for (int ks = 0; ks < 3; ++ks) {
#pragma unroll
    for (int ct = 0; ct < 8; ++ct) {
      s16x8 bb = *(const s16x8*)(bp + ks * 4096 + ct * 512);
      acc[0][ct] = __builtin_amdgcn_mfma_f32_16x16x32_bf16(a[0][ks].v, bb, acc[0][ct], 0, 0, 0);
      acc[1][ct] = __builtin_amdgcn_mfma_f32_16x16x32_bf16(a[1][ks].v, bb, acc[1][ct], 0, 0, 0);
    }
  }

#pragma unroll
  for (int ct = 0; ct < 8; ++ct) {
    int col = colh + ct * 16 + mloc;
    float bv = b[col];
#pragma unroll
    for (int rt = 0; rt < 2; ++rt)
#pragma unroll
      for (int r = 0; r < 4; ++r) {
        int row = row0g + rowl0 + rt * 16 + q * 4 + r;
        if (row < M) hb[(size_t)row * 256 + col] = f2b(acc[rt][ct][r] + bv);
      }
  }
}

// zin_b[v] = bf16((1+eps)h[v] + sum relu(h[src]+ea@W_eff+b_eff))
// ONE WAVE = 4 NODES interleaved; CSR entries AND gather rows software-pipelined:
// loop carries (e,g); per iter loads (en,gn) while FMAing on (e,g) — FMA never waits.
__global__ __launch_bounds__(256) void k_edge_csr(const uint4* __restrict__ csr,
                                                  const int* __restrict__ startv, const int* __restrict__ degv,
                                                  const float* __restrict__ wef, const float* __restrict__ bef,
                                                  const unsigned short* __restrict__ hb,
                                                  unsigned short* __restrict__ zb,
                                                  const float* __restrict__ eps, int layer, int n) {
  int lane = threadIdx.x & 63;
  int wv = threadIdx.x >> 6;
  int v0 = (blockIdx.x * 4 + wv) * 4;
  if (v0 >= n) return;
  int c0 = lane * 4;
  float4 w0 = *(const float4*)(wef + 0 * 256 + c0);
  float4 w1 = *(const float4*)(wef + 1 * 256 + c0);
  float4 w2 = *(const float4*)(wef + 2 * 256 + c0);
  float4 w3 = *(const float4*)(wef + 3 * 256 + c0);
  float4 w4 = *(const float4*)(wef + 4 * 256 + c0);
  float4 w5 = *(const float4*)(wef + 5 * 256 + c0);
  float4 bf = *(const float4*)(bef + c0);
  float s = 1.0f + eps[layer];

  int dg[4], pp[4];
  float4 acc[4];
#pragma unroll
  for (int k = 0; k < 4; ++k) {
    int v = v0 + k;
    dg[k] = degv[v];
    int st = startv[v];
    pp[k] = st < (EE - 1) ? st : (EE - 1);
    uint2 hu = *(const uint2*)(hb + (size_t)v * 256 + c0);
    acc[k].x = s * b2f(hu.x & 0xFFFFu);
    acc[k].y = s * b2f(hu.x >> 16);
    acc[k].z = s * b2f(hu.y & 0xFFFFu);
    acc[k].w = s * b2f(hu.y >> 16);
  }
  int mx = dg[0] > dg[1] ? dg[0] : dg[1];
  int mx2 = dg[2] > dg[3] ? dg[2] : dg[3];
  if (mx2 > mx) mx = mx2;

  uint4 e[4];
  uint2 g[4];
#pragma unroll
  for (int k = 0; k < 4; ++k) e[k] = csr[pp[k]];
#pragma unroll
  for (int k = 0; k < 4; ++k) g[k] = *(const uint2*)(hb + (size_t)(int)e[k].w * 256 + c0);

  for (int t = 0; t < mx; ++t) {
    // prefetch next CSR entries + next gather rows (overlap with FMA on current)
    uint4 en[4];
#pragma unroll
    for (int k = 0; k < 4; ++k) {
      pp[k] += (t < dg[k] - 1) ? 1 : 0;
      en[k] = csr[pp[k]];
    }
    uint2 gn[4];
#pragma unroll
    for (int k = 0; k < 4; ++k) gn[k] = *(const uint2*)(hb + (size_t)(int)en[k].w * 256 + c0);
#pragma unroll
    for (int k = 0; k < 4; ++k) {
      if (t < dg[k]) {
        float a0 = b2f(e[k].x & 0xFFFFu), a1 = b2f(e[k].x >> 16), a2 = b2f(e[k].y & 0xFFFFu);
        float a3 = b2f(e[k].y >> 16), a4 = b2f(e[k].z & 0xFFFFu), a5 = b2f(e[k].z >> 16);
        float mxv = fmaf(a0, w0.x, fmaf(a1, w1.x, fmaf(a2, w2.x, fmaf(a3, w3.x, fmaf(a4, w4.x, fmaf(a5, w5.x, b2f(g[k].x & 0xFFFFu) + bf.x))))));
        float myv = fmaf(a0, w0.y, fmaf(a1, w1.y, fmaf(a2, w2.y, fmaf(a3, w3.y, fmaf(a4, w4.y, fmaf(a5, w5.y, b2f(g[k].x >> 16) + bf.y))))));
        float mzv = fmaf(a0, w0.z, fmaf(a1, w1.z, fmaf(a2, w2.z, fmaf(a3, w3.z, fmaf(a4, w4.z, fmaf(a5, w5.z, b2f(g[k].y & 0xFFFFu) + bf.z))))));
        float mwv = fmaf(a0, w0.w, fmaf(a1, w1.w, fmaf(a2, w2.w, fmaf(a3, w3.w, fmaf(a4, w4.w, fmaf(a5, w5.w, b2f(g[k].y >> 16) + bf.w))))));
        acc[k].x += mxv > 0.f ? mxv : 0.f;
        acc[k].y += myv > 0.f ? myv : 0.f;
        acc[k].z += mzv > 0.f ? mzv : 0.f;
        acc[k].w += mwv > 0.f ? mwv : 0.f;
      }
      e[k] = en[k];
      g[k] = gn[k];
    }
  }
#pragma unroll
  for (int k = 0; k < 4; ++k) {
    uint2 o;
    o.x = (unsigned int)f2b(acc[k].x) | ((unsigned int)f2b(acc[k].y) << 16);
    o.y = (unsigned int)f2b(acc[k].z) | ((unsigned int)f2b(acc[k].w) << 16);
    *(uint2*)(zb + (size_t)(v0 + k) * 256 + c0) = o;
  }
}

// Fused MLP + per-graph stats. Register double-buffered A/B fragment loads
// (launch_bounds(256,3): ~170 combined VGPR+AGPR budget so ks+1 loads stay in flight).
__global__ __launch_bounds__(256, 3) void k_mlp(const unsigned short* __restrict__ A,
                                                const unsigned short* __restrict__ W1p,
                                                const float* __restrict__ b1,
                                                const unsigned short* __restrict__ W2p,
                                                const float* __restrict__ b2,
                                                float* __restrict__ Z,
                                                const int* __restrict__ batchv,
                                                float* __restrict__ S1, float* __restrict__ S2, int M) {
  __shared__ __align__(16) unsigned char smem[33024];        // max(64*256*2, 32*258*4)
  unsigned short* t1s = (unsigned short*)smem;
  float* zc = (float*)smem;                                  // 32 x (stride 258) fp32
  int l = threadIdx.x & 63;
  int w = threadIdx.x >> 6;
  int mloc = l & 15, q = l >> 4;
  int rowg = (w & 1) * 32;
  int colh = (w >> 1) * 128;
  int row0 = blockIdx.x * 64;

  const unsigned short* ap[2];
#pragma unroll
  for (int rt = 0; rt < 2; ++rt) {
    int r = row0 + rowg + rt * 16 + mloc;
    if (r > M - 1) r = M - 1;
    ap[rt] = A + (size_t)r * 256 + q * 8;
  }
  f32x4 acc[2][8];
#pragma unroll
  for (int rt = 0; rt < 2; ++rt)
#pragma unroll
    for (int ct = 0; ct < 8; ++ct) acc[rt][ct] = (f32x4){0.f, 0.f, 0.f, 0.f};

  // ---- GEMM1: A global, B global, both double-buffered in registers ----
  const unsigned short* w1base = W1p + ((size_t)(colh >> 7)) * 32768 + (size_t)l * 8;
  s16x8 bcur[8], bnxt[8];
  s16x8 acur0, acur1, anxt0, anxt1;
#pragma unroll
  for (int ct = 0; ct < 8; ++ct) bcur[ct] = *(const s16x8*)(w1base + ct * 512);
  acur0 = *(const s16x8*)(ap[0]);
  acur1 = *(const s16x8*)(ap[1]);
#pragma unroll
  for (int ks = 0; ks < 8; ++ks) {
    if (ks < 7) {
#pragma unroll
      for (int ct = 0; ct < 8; ++ct) bnxt[ct] = *(const s16x8*)(w1base + (ks + 1) * 4096 + ct * 512);
      anxt0 = *(const s16x8*)(ap[0] + (ks + 1) * 32);
      anxt1 = *(const s16x8*)(ap[1] + (ks + 1) * 32);
    }
#pragma unroll
    for (int ct = 0; ct < 8; ++ct) {
      acc[0][ct] = __builtin_amdgcn_mfma_f32_16x16x32_bf16(acur0, bcur[ct], acc[0][ct], 0, 0, 0);
      acc[1][ct] = __builtin_amdgcn_mfma_f32_16x16x32_bf16(acur1, bcur[ct], acc[1][ct], 0, 0, 0);
    }
    if (ks < 7) {
#pragma unroll
      for (int ct = 0; ct < 8; ++ct) bcur[ct] = bnxt[ct];
      acur0 = anxt0;
      acur1 = anxt1;
    }
  }
  // epilogue 1: bias+relu -> LDS bf16 (XOR swizzle on 16-B chunks)
#pragma unroll
  for (int ct = 0; ct < 8; ++ct) {
    int col = colh + ct * 16 + mloc;
    float bv = b1[col];
    int cc = col >> 3, pos = col & 7;
#pragma unroll
    for (int rt = 0; rt < 2; ++rt)
#pragma unroll
      for (int r = 0; r < 4; ++r) {
        int row = rowg + rt * 16 + q * 4 + r;
        float v = acc[rt][ct][r] + bv;
        v = v > 0.f ? v : 0.f;
        t1s[row * 256 + ((cc ^ (row & 31)) << 3) + pos] = f2b(v);
      }
  }
  __syncthreads();
  // ---- GEMM2: A from LDS, B global double-buffered ----
#pragma unroll
  for (int rt = 0; rt < 2; ++rt)
#pragma unroll
    for (int ct = 0; ct < 8; ++ct) acc[rt][ct] = (f32x4){0.f, 0.f, 0.f, 0.f};
  const unsigned short* w2base = W2p + ((size_t)(colh >> 7)) * 32768 + (size_t)l * 8;
#pragma unroll
  for (int ct = 0; ct < 8; ++ct) bcur[ct] = *(const s16x8*)(w2base + ct * 512);
#pragma unroll
  for (int ks = 0; ks < 8; ++ks) {
    if (ks < 7) {
#pragma unroll
      for (int ct = 0; ct < 8; ++ct) bnxt[ct] = *(const s16x8*)(w2base + (ks + 1) * 4096 + ct * 512);
    }
    s16x8 a[2];
#pragma unroll
    for (int rt = 0; rt < 2; ++rt) {
      int row = rowg + rt * 16 + mloc;
      int cc = (q + ks * 4) ^ (row & 31);
      a[rt] = *(const s16x8*)(t1s + row * 256 + (cc << 3));
    }
#pragma unroll
    for (int ct = 0; ct < 8; ++ct) {
      acc[0][ct] = __builtin_amdgcn_mfma_f32_16x16x32_bf16(a[0], bcur[ct], acc[0][ct], 0, 0, 0);
      acc[1][ct] = __builtin_amdgcn_mfma_f32_16x16x32_bf16(a[1], bcur[ct], acc[1][ct], 0, 0, 0);
    }
    if (ks < 7) {
#pragma unroll
      for (int ct = 0; ct < 8; ++ct) bcur[ct] = bnxt[ct];
    }
  }
  // bias into registers
  float bv2[8];
#pragma unroll
  for (int ct = 0; ct < 8; ++ct) bv2[ct] = b2[colh + ct * 16 + mloc];

  // epilogue 2: bounce through LDS per 32-row half -> coalesced stores + fused stats
#pragma unroll
  for (int half = 0; half < 2; ++half) {
    __syncthreads();
    if ((w & 1) == half) {
#pragma unroll
      for (int ct = 0; ct < 8; ++ct) {
        int col = colh + ct * 16 + mloc;
#pragma unroll
        for (int rt = 0; rt < 2; ++rt)
#pragma unroll
          for (int r = 0; r < 4; ++r) {
            int row = rt * 16 + q * 4 + r;               // 0..31 local
            zc[row * 258 + col] = acc[rt][ct][r] + bv2[ct];
          }
      }
    }
    __syncthreads();
    int baserow = row0 + half * 32;
#pragma unroll
    for (int it = 0; it < 8; ++it) {
      int row = it * 4 + w;                               // one row per wave
      int grow = baserow + row;
      float4 vv = *(const float4*)(zc + row * 258 + l * 4);
      if (grow < M) *(float4*)(Z + (size_t)grow * 256 + l * 4) = vv;
    }
    // fused per-graph S1/S2 (thread = column, segmented by sorted batch)
    {
      int c = threadIdx.x;
      int rend = (M - baserow) < 32 ? (M - baserow) : 32;
      if (rend > 0) {
        float s1 = 0.f, s2 = 0.f;
        int gcur = batchv[baserow];
        for (int row = 0; row < rend; ++row) {
          int g = batchv[baserow + row];
          if (g != gcur) {
            atomicAdd(&S1[(size_t)gcur * 256 + c], s1);
            atomicAdd(&S2[(size_t)gcur * 256 + c], s2);
            s1 = 0.f; s2 = 0.f; gcur = g;
          }
          float v = zc[row * 258 + c];
          s1 += v;
          s2 = fmaf(v, v, s2);
        }
        atomicAdd(&S1[(size_t)gcur * 256 + c], s1);
        atomicAdd(&S2[(size_t)gcur * 256 + c], s2);
      }
    }
  }
}

// attention: score[row] = tanh(h@W1+b1) @ w2 + b2 — fused
__global__ __launch_bounds__(256) void k_att(const unsigned short* __restrict__ A,
                                             const unsigned short* __restrict__ Bp,
                                             const float* __restrict__ b1,
                                             const float* __restrict__ w2,
                                             const float* __restrict__ b2,
                                             float* __restrict__ scores, int M) {
  int l = threadIdx.x & 63;
  int w = threadIdx.x >> 6;
  int mloc = l & 15, q = l >> 4;
  int row0 = blockIdx.x * 128 + w * 32;

  int r0 = row0 + mloc;      if (r0 > M - 1) r0 = M - 1;
  int r1 = row0 + 16 + mloc; if (r1 > M - 1) r1 = M - 1;
  const unsigned short* ap0 = A + (size_t)r0 * 256 + q * 8;
  const unsigned short* ap1 = A + (size_t)r1 * 256 + q * 8;
  const unsigned short* bp = Bp + (size_t)l * 8;

  f32x4 acc[2][8];
#pragma unroll
  for (int rt = 0; rt < 2; ++rt)
#pragma unroll
    for (int ct = 0; ct < 8; ++ct) acc[rt][ct] = (f32x4){0.f, 0.f, 0.f, 0.f};
#pragma unroll
  for (int ks = 0; ks < 8; ++ks) {
    s16x8 a0 = *(const s16x8*)(ap0 + ks * 32);
    s16x8 a1 = *(const s16x8*)(ap1 + ks * 32);
#pragma unroll
    for (int ct = 0; ct < 8; ++ct) {
      s16x8 b = *(const s16x8*)(bp + ks * 4096 + ct * 512);
      acc[0][ct] = __builtin_amdgcn_mfma_f32_16x16x32_bf16(a0, b, acc[0][ct], 0, 0, 0);
      acc[1][ct] = __builtin_amdgcn_mfma_f32_16x16x32_bf16(a1, b, acc[1][ct], 0, 0, 0);
    }
  }
  float bv[8], wv[8];
#pragma unroll
  for (int ct = 0; ct < 8; ++ct) {
    bv[ct] = b1[ct * 16 + mloc];
    wv[ct] = w2[ct * 16 + mloc];
  }
  float b2v = b2[0];
#pragma unroll
  for (int rt = 0; rt < 2; ++rt)
#pragma unroll
    for (int r = 0; r < 4; ++r) {
      float p = 0.0f;
#pragma unroll
      for (int ct = 0; ct < 8; ++ct) p = fmaf(tanhf(acc[rt][ct][r] + bv[ct]), wv[ct], p);
      p += __shfl_xor(p, 1, 64);
      p += __shfl_xor(p, 2, 64);
      p += __shfl_xor(p, 4, 64);
      p += __shfl_xor(p, 8, 64);
      int row = row0 + rt * 16 + q * 4 + r;
      if (mloc == 0 && row < M) scores[row] = p + b2v;
    }
}

// BN partial: block b sums S1/S2 over graphs [b*32,(b+1)*32) — coalesced (thread = column)
__global__ __launch_bounds__(256) void k_bn_part(const float* __restrict__ S1, const float* __restrict__ S2,
                                                 float* __restrict__ P1, float* __restrict__ P2) {
  int b = blockIdx.x, c = threadIdx.x;
  float s1 = 0.0f, s2 = 0.0f;
  for (int g = b * 32; g < b * 32 + 32; ++g) {
    s1 += S1[(size_t)g * 256 + c];
    s2 += S2[(size_t)g * 256 + c];
  }
  P1[(size_t)b * 256 + c] = s1;
  P2[(size_t)b * 256 + c] = s2;
}

// BN finalize: fold 64 partials per column, compute abuf/bbuf (thread = column, no reduce)
__global__ __launch_bounds__(256) void k_bn_fin2(const float* __restrict__ P1, const float* __restrict__ P2,
                                                 const float* __restrict__ gamma, const float* __restrict__ beta,
                                                 float* __restrict__ abuf, float* __restrict__ bbuf, int n) {
  int c = threadIdx.x;
  float s1 = 0.0f, s2 = 0.0f;
  for (int r = 0; r < 64; ++r) {
    s1 += P1[(size_t)r * 256 + c];
    s2 += P2[(size_t)r * 256 + c];
  }
  float inv = 1.0f / (float)n;
  float mu = s1 * inv;
  float var = s2 * inv - mu * mu;
  float rstd = rsqrtf(var + 1e-5f);
  float a = gamma[c] * rstd;
  abuf[c] = a;
  bbuf[c] = beta[c] - mu * a;
}

// per-graph: gmean/rinv from S1/S2 in-block, apply BN+PairNorm+relu; zeroes S1/S2 for next layer.
template <int LAST>
__global__ __launch_bounds__(256) void k_apply(float* __restrict__ z, const float* __restrict__ abuf,
                                               const float* __restrict__ bbuf, const int* __restrict__ gstart,
                                               const int* __restrict__ cnti, const float* __restrict__ cntf,
                                               float* __restrict__ S1, float* __restrict__ S2,
                                               unsigned short* __restrict__ hb) {
  __shared__ float rT[256], rM[256];
  int g = blockIdx.x, c = threadIdx.x;
  float a = abuf[c], b = bbuf[c];
  size_t idx = (size_t)g * 256 + c;
  float s1 = S1[idx];
  float s2 = S2[idx];
  S1[idx] = 0.0f;          // re-zero for next layer's fused stats
  S2[idx] = 0.0f;
  float nr = (float)cnti[g];
  float ic = 1.0f / cntf[g];
  float mean = (a * s1 + nr * b) * ic;
  float term = fmaf(a * a, s2, fmaf(2.0f * a * b, s1, nr * b * b));
  rT[c] = term;
  rM[c] = mean * mean;
  __syncthreads();
  for (int off = 128; off; off >>= 1) {
    if (c < off) { rT[c] += rT[c + off]; rM[c] += rM[c + off]; }
    __syncthreads();
  }
  float cr = nr > 0.0f ? 1.0f : 0.0f;
  float rinv = rsqrtf(1e-5f + rT[0] * ic - cr * rM[0]);
  int r0 = gstart[g], r1 = r0 + cnti[g];
  for (int r = r0; r < r1; ++r) {
    float v = (fmaf(a, z[(size_t)r * 256 + c], b) - mean) * rinv;
    v = v > 0.0f ? v : 0.0f;
    hb[(size_t)r * 256 + c] = f2b(v);
    if (LAST) z[(size_t)r * 256 + c] = v;
  }
}

// per-graph fused pooling + output
__global__ __launch_bounds__(256) void k_poolout(const float* __restrict__ h, const float* __restrict__ scores,
                                                 const int* __restrict__ gstart, const int* __restrict__ cnti,
                                                 const float* __restrict__ cntf, float* __restrict__ out) {
  int g = blockIdx.x, c = threadIdx.x;
  int r0 = gstart[g], r1 = r0 + cnti[g];
  float ma = 0.0f, aa = 0.0f, mx = 0.0f, wa = 0.0f;
  for (int r = r0; r < r1; ++r) {
    float wgt = __expf(scores[r]);
    float hv = h[(size_t)r * 256 + c];
    ma += hv;
    aa = fmaf(hv, wgt, aa);
    mx = fmaxf(mx, hv);
    wa += wgt;
  }
  out[(size_t)g * 768 + c] = ma / cntf[g];
  out[(size_t)g * 768 + 256 + c] = mx;
  out[(size_t)g * 768 + 512 + c] = aa / (wa + 1e-8f);
}

extern "C" void kernel_launch(void* const* d_in, const int* in_sizes, int n_in,
                              void* d_out, int out_size, void* d_ws, size_t ws_size,
                              hipStream_t stream) {
  const float* x         = (const float*)d_in[0];
  const float* edge_attr = (const float*)d_in[1];
  const float* node_w    = (const float*)d_in[2];
  const float* node_b    = (const float*)d_in[3];
  const float* edge_w    = (const float*)d_in[4];
  const float* edge_b    = (const float*)d_in[5];
  const float* conv_w    = (const float*)d_in[6];
  const float* conv_b    = (const float*)d_in[7];
  const float* mlp_w1    = (const float*)d_in[8];
  const float* mlp_b1    = (const float*)d_in[9];
  const float* mlp_w2    = (const float*)d_in[10];
  const float* mlp_b2    = (const float*)d_in[11];
  const float* eps       = (const float*)d_in[12];
  const float* bn_gamma  = (const float*)d_in[13];
  const float* bn_beta   = (const float*)d_in[14];
  const float* att_w1    = (const float*)d_in[15];
  const float* att_b1    = (const float*)d_in[16];
  const float* att_w2    = (const float*)d_in[17];
  const float* att_b2    = (const float*)d_in[18];
  const int*   eidx      = (const int*)d_in[19];
  const int*   batch     = (const int*)d_in[20];
  float* out = (float*)d_out;
  float* ws  = (float*)d_ws;

  float*          zbuf = ws + O_Z;
  unsigned short* zb   = (unsigned short*)(ws + O_ZB);
  unsigned short* hb   = (unsigned short*)(ws + O_HB);
  float* S1    = ws + O_S1;
  float* S2    = ws + O_S2;
  float* abuf  = ws + O_ABUF;
  float* bbuf  = ws + O_BBUF;
  int*   cnti  = (int*)(ws + O_CNTI);
  float* cntf  = ws + O_CNTF;
  float* scor  = ws + O_SCOR;
  int*   curs  = (int*)(ws + O_SCOR);
  float* weff  = ws + O_WEFF;
  float* beff  = ws + O_BEFF;
  int*   deg   = (int*)(ws + O_DEG);
  int*   strt  = (int*)(ws + O_STRT);
  int*   bsum  = (int*)(ws + O_BSUM);
  uint4* csr   = (uint4*)(ws + O_CSR);
  unsigned short* w1p = (unsigned short*)(ws + O_W1P);
  unsigned short* w2p = (unsigned short*)(ws + O_W2P);
  unsigned short* atp = (unsigned short*)(ws + O_ATP);
  int*   gst   = (int*)(ws + O_GST);
  unsigned short* nwp = (unsigned short*)(ws + O_NWP);
  float* bnp1  = ws + O_BNP;
  float* bnp2  = ws + O_BNP + 16384;
  const int* esrc = eidx;
  const int* edst = eidx + EE;

  // graph counts + offsets
  k_zero<<<8, 256, 0, stream>>>((float*)cnti, GG);
  k_count<<<(NN + 255) / 256, 256, 0, stream>>>(batch, cnti, NN);
  k_gscan<<<1, 256, 0, stream>>>(cnti, gst, cntf);

  // fused edge weights + weight packing + MFMA node embedding
  k_wfuse<<<LL, 256, 0, stream>>>(edge_w, edge_b, conv_w, conv_b, weff, beff);
  k_pack_all<<<528, 256, 0, stream>>>(mlp_w1, mlp_w2, att_w1, w1p, w2p, atp);
  k_pack_node<<<12, 256, 0, stream>>>(node_w, nwp);
  k_embed_mfma<<<(NN + 63) / 64, 256, 0, stream>>>(x, nwp, node_b, hb, NN);

  // S1/S2 zero for layer-0 fused stats (subsequent layers re-zeroed by k_apply)
  k_zero<<<1024, 256, 0, stream>>>(S1, 2 * 524288);

  // CSR build (by dst)
  const int nscan = (NN + 255) / 256;  // 391
  k_zero<<<256, 256, 0, stream>>>((float*)deg, NN);
  k_deg<<<(EE + 255) / 256, 256, 0, stream>>>(edst, deg, EE);
  k_scan_part<<<nscan, 256, 0, stream>>>(deg, strt, bsum, NN);
  k_scan_top<<<1, 512, 0, stream>>>(bsum, nscan);
  k_scan_add<<<nscan, 256, 0, stream>>>(strt, bsum, curs, NN);
  k_fill<<<(EE + 255) / 256, 256, 0, stream>>>(edge_attr, esrc, edst, curs, csr, EE);

  const int mtiles64  = (NN + 63) / 64;    // 1563
  const int mtiles128 = (NN + 127) / 128;  // 782

  for (int i = 0; i < LL; ++i) {
    k_edge_csr<<<NN / 16, 256, 0, stream>>>(csr, strt, deg, weff + (size_t)i * 1536,
                                            beff + (size_t)i * 256, hb, zb, eps, i, NN);
    k_mlp<<<mtiles64, 256, 0, stream>>>(zb, w1p + (size_t)i * 65536, mlp_b1 + (size_t)i * 256,
                                        w2p + (size_t)i * 65536, mlp_b2 + (size_t)i * 256, zbuf,
                                        batch, S1, S2, NN);
    k_bn_part<<<64, 256, 0, stream>>>(S1, S2, bnp1, bnp2);
    k_bn_fin2<<<1, 256, 0, stream>>>(bnp1, bnp2, bn_gamma + (size_t)i * 256,
                                     bn_beta + (size_t)i * 256, abuf, bbuf, NN);
    if (i == LL - 1)
      k_apply<1><<<GG, 256, 0, stream>>>(zbuf, abuf, bbuf, gst, cnti, cntf, S1, S2, hb);
    else
      k_apply<0><<<GG, 256, 0, stream>>>(zbuf, abuf, bbuf, gst, cnti, cntf, S1, S2, hb);
  }

  // pooling (zbuf holds fp32 h)
  k_att<<<mtiles128, 256, 0, stream>>>(hb, atp, att_b1, att_w2, att_b2, scor, NN);
  k_poolout<<<GG, 256, 0, stream>>>(zbuf, scor, gst, cnti, cntf, out);
}

// Round 12
// 1560.553 us; speedup vs baseline: 1.1679x; 1.1679x over previous
//
#include <hip/hip_runtime.h>
#include <cstdint>
#include <cstddef>

// Problem constants (fixed instance)
#define NN 100000
#define EE 320000
#define GG 2048
#define LL 8

// Workspace layout (float offsets).
#define O_Z    0ull                      // [N,256] fp32 z; h fp32 (in-place) after last apply
#define O_ZB   25600000ull               // [N,256] bf16 zin
#define O_HB   38400000ull               // [N,256] bf16 h
#define O_S1   51200000ull               // [G,256] S1
#define O_S2   (O_S1 + 524288ull)        // [G,256] S2
#define O_ABUF (O_S2 + 524288ull)        // [256]
#define O_BBUF (O_ABUF + 256ull)         // [256]
#define O_CNTI (O_BBUF + 256ull)         // [G] int
#define O_CNTF (O_CNTI + 2048ull)        // [G]
#define O_SCOR (O_CNTF + 2048ull)        // [N] scores (CSR cursor during setup)
#define O_WEFF (O_SCOR + 100000ull)      // [L,6,256]
#define O_BEFF (O_WEFF + 12288ull)       // [L,256]
#define O_DEG  (O_BEFF + 2048ull)        // [N] int
#define O_STRT (O_DEG + 100000ull)       // [N] int
#define O_BSUM (O_STRT + 100000ull)      // [512] int
#define O_CSR  (O_BSUM + 512ull)         // [E] x 16 B: 6 bf16 attrs + int src
#define O_W1P  (O_CSR + 1280000ull)      // 8 x 65536 bf16 = 262144 floats
#define O_W2P  (O_W1P + 262144ull)
#define O_ATP  (O_W2P + 262144ull)       // 32768 shorts = 16384 floats
#define O_GST  (O_ATP + 16384ull)        // [G] int gstart
#define O_NWP  (O_GST + 2048ull)         // node_w packed: 24576 shorts = 12288 floats
#define O_BNP  (O_NWP + 12288ull)        // bn partials: 2 x [64,256] = 32768 floats

typedef short s16x8 __attribute__((ext_vector_type(8)));
typedef float f32x4 __attribute__((ext_vector_type(4)));

__device__ inline float b2f(unsigned int lo16) {
  union { float f; unsigned int u; } x; x.u = lo16 << 16; return x.f;
}
__device__ inline unsigned short f2b(float f) {
  union { float f; unsigned int u; } x; x.f = f;
  unsigned int r = x.u + 0x7FFFu + ((x.u >> 16) & 1u);
  return (unsigned short)(r >> 16);
}
__device__ inline unsigned short f2b_lo(float v) {   // residual after bf16 hi
  unsigned short h = f2b(v);
  float hf = b2f((unsigned int)h);
  return f2b(v - hf);
}

__global__ __launch_bounds__(256) void k_zero(float* __restrict__ p, int n) {
  int i = blockIdx.x * 256 + threadIdx.x;
  int stride = gridDim.x * 256;
  for (; i < n; i += stride) p[i] = 0.0f;
}

__global__ __launch_bounds__(256) void k_count(const int* __restrict__ batch, int* __restrict__ cnti, int n) {
  int i = blockIdx.x * 256 + threadIdx.x;
  if (i < n) atomicAdd(&cnti[batch[i]], 1);
}

// single-block scan over G=2048 counts -> gstart (exclusive), cntf (clamped)
__global__ __launch_bounds__(256) void k_gscan(const int* __restrict__ cnti, int* __restrict__ gstart,
                                               float* __restrict__ cntf) {
  __shared__ int part[256];
  int t = threadIdx.x;
  int base = t * 8;
  int loc[8];
  int s = 0;
#pragma unroll
  for (int i = 0; i < 8; ++i) { loc[i] = s; s += cnti[base + i]; }
  part[t] = s;
  __syncthreads();
  for (int off = 1; off < 256; off <<= 1) {
    int u = (t >= off) ? part[t - off] : 0;
    __syncthreads();
    part[t] += u;
    __syncthreads();
  }
  int p = (t > 0) ? part[t - 1] : 0;
#pragma unroll
  for (int i = 0; i < 8; ++i) {
    gstart[base + i] = p + loc[i];
    float v = (float)cnti[base + i];
    cntf[base + i] = v > 1.0f ? v : 1.0f;
  }
}

// ---------------- CSR build ----------------
__global__ __launch_bounds__(256) void k_deg(const int* __restrict__ edst, int* __restrict__ deg, int ne) {
  int e = blockIdx.x * 256 + threadIdx.x;
  if (e < ne) atomicAdd(&deg[edst[e]], 1);
}

__global__ __launch_bounds__(256) void k_scan_part(const int* __restrict__ deg, int* __restrict__ start,
                                                   int* __restrict__ bsum, int n) {
  __shared__ int s[256];
  int i = blockIdx.x * 256 + threadIdx.x;
  int t = threadIdx.x;
  int v = (i < n) ? deg[i] : 0;
  s[t] = v;
  __syncthreads();
  for (int off = 1; off < 256; off <<= 1) {
    int u = (t >= off) ? s[t - off] : 0;
    __syncthreads();
    s[t] += u;
    __syncthreads();
  }
  if (i < n) start[i] = s[t] - v;
  if (t == 255) bsum[blockIdx.x] = s[255];
}

__global__ __launch_bounds__(512) void k_scan_top(int* __restrict__ bsum, int nb) {
  __shared__ int s[512];
  int t = threadIdx.x;
  int v = (t < nb) ? bsum[t] : 0;
  s[t] = v;
  __syncthreads();
  for (int off = 1; off < 512; off <<= 1) {
    int u = (t >= off) ? s[t - off] : 0;
    __syncthreads();
    s[t] += u;
    __syncthreads();
  }
  if (t < nb) bsum[t] = s[t] - v;
}

__global__ __launch_bounds__(256) void k_scan_add(int* __restrict__ start, const int* __restrict__ bsum,
                                                  int* __restrict__ cursor, int n) {
  int i = blockIdx.x * 256 + threadIdx.x;
  if (i < n) {
    int v = start[i] + bsum[blockIdx.x];
    start[i] = v;
    cursor[i] = v;
  }
}

// CSR entry: uint4 = {attr0|attr1<<16, attr2|attr3<<16, attr4|attr5<<16, src}
__global__ __launch_bounds__(256) void k_fill(const float* __restrict__ ea, const int* __restrict__ esrc,
                                              const int* __restrict__ edst, int* __restrict__ cursor,
                                              uint4* __restrict__ csr, int ne) {
  int e = blockIdx.x * 256 + threadIdx.x;
  if (e >= ne) return;
  int d = edst[e];
  int slot = atomicAdd(&cursor[d], 1);
  const float* ap = ea + (size_t)e * 6;
  uint4 v;
  v.x = (unsigned int)f2b(ap[0]) | ((unsigned int)f2b(ap[1]) << 16);
  v.y = (unsigned int)f2b(ap[2]) | ((unsigned int)f2b(ap[3]) << 16);
  v.z = (unsigned int)f2b(ap[4]) | ((unsigned int)f2b(ap[5]) << 16);
  v.w = (unsigned int)esrc[e];
  csr[slot] = v;
}

// W_eff[i] = edge_w @ conv_w[i]; b_eff[i] = edge_b @ conv_w[i] + conv_b[i]
__global__ __launch_bounds__(256) void k_wfuse(const float* __restrict__ edge_w, const float* __restrict__ edge_b,
                                               const float* __restrict__ conv_w, const float* __restrict__ conv_b,
                                               float* __restrict__ wef, float* __restrict__ bef) {
  __shared__ float ew[6 * 128 + 128];
  int i = blockIdx.x;
  int c = threadIdx.x;
  for (int idx = c; idx < 896; idx += 256)
    ew[idx] = idx < 768 ? edge_w[idx] : edge_b[idx - 768];
  __syncthreads();
  float acc[7] = {0.f, 0.f, 0.f, 0.f, 0.f, 0.f, 0.f};
  const float* cw = conv_w + (size_t)i * 32768 + c;
  for (int j = 0; j < 128; ++j) {
    float w = cw[(size_t)j * 256];
#pragma unroll
    for (int k = 0; k < 6; ++k) acc[k] = fmaf(ew[k * 128 + j], w, acc[k]);
    acc[6] = fmaf(ew[768 + j], w, acc[6]);
  }
#pragma unroll
  for (int k = 0; k < 6; ++k) wef[(size_t)i * 1536 + k * 256 + c] = acc[k];
  bef[(size_t)i * 256 + c] = acc[6] + conv_b[(size_t)i * 256 + c];
}

// pack ALL mlp/att weights to MFMA B-fragment order in one launch.
__global__ __launch_bounds__(256) void k_pack_all(const float* __restrict__ mw1, const float* __restrict__ mw2,
                                                  const float* __restrict__ aw1,
                                                  unsigned short* __restrict__ w1p,
                                                  unsigned short* __restrict__ w2p,
                                                  unsigned short* __restrict__ atp) {
  int id = blockIdx.x * 256 + threadIdx.x;   // 33*4096 total
  int cbu = id >> 12;
  if (cbu >= 33) return;
  int lid = id & 4095;
  int l = lid & 63;
  int ct = (lid >> 6) & 7;
  int ks = (lid >> 9) & 7;
  const float* B;
  unsigned short* Bp;
  int ldb, cb;
  if (cbu < 32) {
    int m = cbu >> 1;
    cb = cbu & 1;
    ldb = 256;
    if (m < 8) { B = mw1 + (size_t)m * 65536; Bp = w1p + (size_t)m * 65536; }
    else       { B = mw2 + (size_t)(m - 8) * 65536; Bp = w2p + (size_t)(m - 8) * 65536; }
  } else {
    B = aw1; Bp = atp; ldb = 128; cb = 0;
  }
  int n = cb * 128 + ct * 16 + (l & 15);
  int k0 = ks * 32 + (l >> 4) * 8;
  unsigned short* dst = Bp + (((size_t)cb << 12) | (size_t)lid) * 8;
#pragma unroll
  for (int j = 0; j < 8; ++j) dst[j] = f2b(B[(size_t)(k0 + j) * ldb + n]);
}

// pack node_w [48,256] -> bf16 K_eff=96 fragment order: [cb][ks3][ct][lane][8]
__global__ __launch_bounds__(256) void k_pack_node(const float* __restrict__ w,
                                                   unsigned short* __restrict__ Wp) {
  int id = blockIdx.x * 256 + threadIdx.x;   // 3072 total
  if (id >= 3072) return;
  int l = id & 63;
  int t = id >> 6;
  int ct = t & 7;
  int u = t >> 3;          // 0..5
  int ks = u % 3;
  int cb = u / 3;
  int n = cb * 128 + ct * 16 + (l & 15);
  unsigned short* dst = Wp + (size_t)id * 8;
#pragma unroll
  for (int j = 0; j < 8; ++j) {
    int kk = ks * 32 + ((l >> 4) << 3) + j;
    int ksrc = kk < 48 ? kk : kk - 48;
    dst[j] = f2b(w[(size_t)ksrc * 256 + n]);
  }
}

// hb = bf16(x @ node_w + node_b) via MFMA, x staged through LDS (coalesced global reads).
__global__ __launch_bounds__(256) void k_embed_mfma(const float* __restrict__ x,
                                                    const unsigned short* __restrict__ Wp,
                                                    const float* __restrict__ b,
                                                    unsigned short* __restrict__ hb, int M) {
  __shared__ float xs[64 * 50];                 // stride 50 to spread banks
  int tid = threadIdx.x;
  int row0g = blockIdx.x * 64;
  for (int idx = tid; idx < 3072; idx += 256) {
    int r = idx / 48, c = idx - r * 48;
    int gr = row0g + r; if (gr > M - 1) gr = M - 1;
    xs[r * 50 + c] = x[(size_t)gr * 48 + c];
  }
  __syncthreads();

  int l = tid & 63;
  int w = tid >> 6;
  int mloc = l & 15, q = l >> 4;
  int rowl0 = (w & 1) * 32;
  int colh = (w >> 1) * 128;

  f32x4 acc[2][8];
#pragma unroll
  for (int rt = 0; rt < 2; ++rt)
#pragma unroll
    for (int ct = 0; ct < 8; ++ct) acc[rt][ct] = (f32x4){0.f, 0.f, 0.f, 0.f};

  union { s16x8 v; unsigned short u[8]; } a[2][3];
#pragma unroll
  for (int rt = 0; rt < 2; ++rt) {
    const float* xr = xs + (rowl0 + rt * 16 + mloc) * 50;
    const float* p0 = xr + q * 8;
    const float* p1 = xr + (q < 2 ? 32 + q * 8 : (q - 2) * 8);
    const float* p2 = xr + 16 + q * 8;
#pragma unroll
    for (int j = 0; j < 8; ++j) {
      a[rt][0].u[j] = f2b(p0[j]);
      a[rt][1].u[j] = (q < 2) ? f2b(p1[j]) : f2b_lo(p1[j]);
      a[rt][2].u[j] = f2b_lo(p2[j]);
    }
  }

  const unsigned short* bp = Wp + (size_t)(colh >> 7) * 12288 + (size_t)l * 8;
#pragma unroll
  for (int ks = 0; ks < 3; ++ks) {
#pragma unroll
    for (int ct = 0; ct < 8; ++ct) {
      s16x8 bb = *(const s16x8*)(bp + ks * 4096 + ct * 512);
      acc[0][ct] = __builtin_amdgcn_mfma_f32_16x16x32_bf16(a[0][ks].v, bb, acc[0][ct], 0, 0, 0);
      acc[1][ct] = __builtin_amdgcn_mfma_f32_16x16x32_bf16(a[1][ks].v, bb, acc[1][ct], 0, 0, 0);
    }
  }

#pragma unroll
  for (int ct = 0; ct < 8; ++ct) {
    int col = colh + ct * 16 + mloc;
    float bv = b[col];
#pragma unroll
    for (int rt = 0; rt < 2; ++rt)
#pragma unroll
      for (int r = 0; r < 4; ++r) {
        int row = row0g + rowl0 + rt * 16 + q * 4 + r;
        if (row < M) hb[(size_t)row * 256 + col] = f2b(acc[rt][ct][r] + bv);
      }
  }
}

// zin_b[v] = bf16((1+eps)h[v] + sum relu(h[src]+ea@W_eff+b_eff))
// ONE WAVE = 4 NODES interleaved; CSR entries software-pipelined (csr[t+1] loads
// issue during gather(t)+FMA(t)).  [R10 form — gather prefetch reverted]
__global__ __launch_bounds__(256) void k_edge_csr(const uint4* __restrict__ csr,
                                                  const int* __restrict__ startv, const int* __restrict__ degv,
                                                  const float* __restrict__ wef, const float* __restrict__ bef,
                                                  const unsigned short* __restrict__ hb,
                                                  unsigned short* __restrict__ zb,
                                                  const float* __restrict__ eps, int layer, int n) {
  int lane = threadIdx.x & 63;
  int wv = threadIdx.x >> 6;
  int v0 = (blockIdx.x * 4 + wv) * 4;
  if (v0 >= n) return;
  int c0 = lane * 4;
  float4 w0 = *(const float4*)(wef + 0 * 256 + c0);
  float4 w1 = *(const float4*)(wef + 1 * 256 + c0);
  float4 w2 = *(const float4*)(wef + 2 * 256 + c0);
  float4 w3 = *(const float4*)(wef + 3 * 256 + c0);
  float4 w4 = *(const float4*)(wef + 4 * 256 + c0);
  float4 w5 = *(const float4*)(wef + 5 * 256 + c0);
  float4 bf = *(const float4*)(bef + c0);
  float s = 1.0f + eps[layer];

  int dg[4], pp[4];
  float4 acc[4];
#pragma unroll
  for (int k = 0; k < 4; ++k) {
    int v = v0 + k;
    dg[k] = degv[v];
    int st = startv[v];
    pp[k] = st < (EE - 1) ? st : (EE - 1);
    uint2 hu = *(const uint2*)(hb + (size_t)v * 256 + c0);
    acc[k].x = s * b2f(hu.x & 0xFFFFu);
    acc[k].y = s * b2f(hu.x >> 16);
    acc[k].z = s * b2f(hu.y & 0xFFFFu);
    acc[k].w = s * b2f(hu.y >> 16);
  }
  int mx = dg[0] > dg[1] ? dg[0] : dg[1];
  int mx2 = dg[2] > dg[3] ? dg[2] : dg[3];
  if (mx2 > mx) mx = mx2;

  uint4 e[4];
#pragma unroll
  for (int k = 0; k < 4; ++k) e[k] = csr[pp[k]];

  for (int t = 0; t < mx; ++t) {
    uint2 g[4];
#pragma unroll
    for (int k = 0; k < 4; ++k) g[k] = *(const uint2*)(hb + (size_t)(int)e[k].w * 256 + c0);
    // advance pointers and prefetch next CSR entries (overlap with FMA below)
    uint4 en[4];
#pragma unroll
    for (int k = 0; k < 4; ++k) {
      pp[k] += (t < dg[k] - 1) ? 1 : 0;
      en[k] = csr[pp[k]];
    }
#pragma unroll
    for (int k = 0; k < 4; ++k) {
      if (t < dg[k]) {
        float a0 = b2f(e[k].x & 0xFFFFu), a1 = b2f(e[k].x >> 16), a2 = b2f(e[k].y & 0xFFFFu);
        float a3 = b2f(e[k].y >> 16), a4 = b2f(e[k].z & 0xFFFFu), a5 = b2f(e[k].z >> 16);
        float mxv = fmaf(a0, w0.x, fmaf(a1, w1.x, fmaf(a2, w2.x, fmaf(a3, w3.x, fmaf(a4, w4.x, fmaf(a5, w5.x, b2f(g[k].x & 0xFFFFu) + bf.x))))));
        float myv = fmaf(a0, w0.y, fmaf(a1, w1.y, fmaf(a2, w2.y, fmaf(a3, w3.y, fmaf(a4, w4.y, fmaf(a5, w5.y, b2f(g[k].x >> 16) + bf.y))))));
        float mzv = fmaf(a0, w0.z, fmaf(a1, w1.z, fmaf(a2, w2.z, fmaf(a3, w3.z, fmaf(a4, w4.z, fmaf(a5, w5.z, b2f(g[k].y & 0xFFFFu) + bf.z))))));
        float mwv = fmaf(a0, w0.w, fmaf(a1, w1.w, fmaf(a2, w2.w, fmaf(a3, w3.w, fmaf(a4, w4.w, fmaf(a5, w5.w, b2f(g[k].y >> 16) + bf.w))))));
        acc[k].x += mxv > 0.f ? mxv : 0.f;
        acc[k].y += myv > 0.f ? myv : 0.f;
        acc[k].z += mzv > 0.f ? mzv : 0.f;
        acc[k].w += mwv > 0.f ? mwv : 0.f;
      }
      e[k] = en[k];
    }
  }
#pragma unroll
  for (int k = 0; k < 4; ++k) {
    uint2 o;
    o.x = (unsigned int)f2b(acc[k].x) | ((unsigned int)f2b(acc[k].y) << 16);
    o.y = (unsigned int)f2b(acc[k].z) | ((unsigned int)f2b(acc[k].w) << 16);
    *(uint2*)(zb + (size_t)(v0 + k) * 256 + c0) = o;
  }
}

// Fused MLP + per-graph stats [R10 form — (256,4), no manual double-buffering;
// compiler's own scheduling proved better than source-level prefetch in R11].
__global__ __launch_bounds__(256, 4) void k_mlp(const unsigned short* __restrict__ A,
                                                const unsigned short* __restrict__ W1p,
                                                const float* __restrict__ b1,
                                                const unsigned short* __restrict__ W2p,
                                                const float* __restrict__ b2,
                                                float* __restrict__ Z,
                                                const int* __restrict__ batchv,
                                                float* __restrict__ S1, float* __restrict__ S2, int M) {
  __shared__ __align__(16) unsigned char smem[33024];        // max(64*256*2, 32*258*4)
  unsigned short* t1s = (unsigned short*)smem;
  float* zc = (float*)smem;                                  // 32 x (stride 258) fp32
  int l = threadIdx.x & 63;
  int w = threadIdx.x >> 6;
  int mloc = l & 15, q = l >> 4;
  int rowg = (w & 1) * 32;
  int colh = (w >> 1) * 128;
  int row0 = blockIdx.x * 64;

  const unsigned short* ap[2];
#pragma unroll
  for (int rt = 0; rt < 2; ++rt) {
    int r = row0 + rowg + rt * 16 + mloc;
    if (r > M - 1) r = M - 1;
    ap[rt] = A + (size_t)r * 256 + q * 8;
  }
  f32x4 acc[2][8];
#pragma unroll
  for (int rt = 0; rt < 2; ++rt)
#pragma unroll
    for (int ct = 0; ct < 8; ++ct) acc[rt][ct] = (f32x4){0.f, 0.f, 0.f, 0.f};

  const unsigned short* w1base = W1p + ((size_t)(colh >> 7)) * 32768 + (size_t)l * 8;
#pragma unroll
  for (int ks = 0; ks < 8; ++ks) {
    s16x8 a0 = *(const s16x8*)(ap[0] + ks * 32);
    s16x8 a1 = *(const s16x8*)(ap[1] + ks * 32);
#pragma unroll
    for (int ct = 0; ct < 8; ++ct) {
      s16x8 b = *(const s16x8*)(w1base + ks * 4096 + ct * 512);
      acc[0][ct] = __builtin_amdgcn_mfma_f32_16x16x32_bf16(a0, b, acc[0][ct], 0, 0, 0);
      acc[1][ct] = __builtin_amdgcn_mfma_f32_16x16x32_bf16(a1, b, acc[1][ct], 0, 0, 0);
    }
  }
  // epilogue 1: bias+relu -> LDS bf16 (XOR swizzle on 16-B chunks)
#pragma unroll
  for (int ct = 0; ct < 8; ++ct) {
    int col = colh + ct * 16 + mloc;
    float bv = b1[col];
    int cc = col >> 3, pos = col & 7;
#pragma unroll
    for (int rt = 0; rt < 2; ++rt)
#pragma unroll
      for (int r = 0; r < 4; ++r) {
        int row = rowg + rt * 16 + q * 4 + r;
        float v = acc[rt][ct][r] + bv;
        v = v > 0.f ? v : 0.f;
        t1s[row * 256 + ((cc ^ (row & 31)) << 3) + pos] = f2b(v);
      }
  }
  __syncthreads();
  // GEMM2: A from LDS
#pragma unroll
  for (int rt = 0; rt < 2; ++rt)
#pragma unroll
    for (int ct = 0; ct < 8; ++ct) acc[rt][ct] = (f32x4){0.f, 0.f, 0.f, 0.f};
  const unsigned short* w2base = W2p + ((size_t)(colh >> 7)) * 32768 + (size_t)l * 8;
#pragma unroll
  for (int ks = 0; ks < 8; ++ks) {
    s16x8 a[2];
#pragma unroll
    for (int rt = 0; rt < 2; ++rt) {
      int row = rowg + rt * 16 + mloc;
      int cc = (q + ks * 4) ^ (row & 31);
      a[rt] = *(const s16x8*)(t1s + row * 256 + (cc << 3));
    }
#pragma unroll
    for (int ct = 0; ct < 8; ++ct) {
      s16x8 b = *(const s16x8*)(w2base + ks * 4096 + ct * 512);
      acc[0][ct] = __builtin_amdgcn_mfma_f32_16x16x32_bf16(a[0], b, acc[0][ct], 0, 0, 0);
      acc[1][ct] = __builtin_amdgcn_mfma_f32_16x16x32_bf16(a[1], b, acc[1][ct], 0, 0, 0);
    }
  }
  // bias into registers
  float bv2[8];
#pragma unroll
  for (int ct = 0; ct < 8; ++ct) bv2[ct] = b2[colh + ct * 16 + mloc];

  // epilogue 2: bounce through LDS per 32-row half -> coalesced stores + fused stats
#pragma unroll
  for (int half = 0; half < 2; ++half) {
    __syncthreads();
    if ((w & 1) == half) {
#pragma unroll
      for (int ct = 0; ct < 8; ++ct) {
        int col = colh + ct * 16 + mloc;
#pragma unroll
        for (int rt = 0; rt < 2; ++rt)
#pragma unroll
          for (int r = 0; r < 4; ++r) {
            int row = rt * 16 + q * 4 + r;               // 0..31 local
            zc[row * 258 + col] = acc[rt][ct][r] + bv2[ct];
          }
      }
    }
    __syncthreads();
    int baserow = row0 + half * 32;
#pragma unroll
    for (int it = 0; it < 8; ++it) {
      int row = it * 4 + w;                               // one row per wave
      int grow = baserow + row;
      float4 vv = *(const float4*)(zc + row * 258 + l * 4);
      if (grow < M) *(float4*)(Z + (size_t)grow * 256 + l * 4) = vv;
    }
    // fused per-graph S1/S2 (thread = column, segmented by sorted batch)
    {
      int c = threadIdx.x;
      int rend = (M - baserow) < 32 ? (M - baserow) : 32;
      if (rend > 0) {
        float s1 = 0.f, s2 = 0.f;
        int gcur = batchv[baserow];
        for (int row = 0; row < rend; ++row) {
          int g = batchv[baserow + row];
          if (g != gcur) {
            atomicAdd(&S1[(size_t)gcur * 256 + c], s1);
            atomicAdd(&S2[(size_t)gcur * 256 + c], s2);
            s1 = 0.f; s2 = 0.f; gcur = g;
          }
          float v = zc[row * 258 + c];
          s1 += v;
          s2 = fmaf(v, v, s2);
        }
        atomicAdd(&S1[(size_t)gcur * 256 + c], s1);
        atomicAdd(&S2[(size_t)gcur * 256 + c], s2);
      }
    }
  }
}

// attention: score[row] = tanh(h@W1+b1) @ w2 + b2 — fused
__global__ __launch_bounds__(256) void k_att(const unsigned short* __restrict__ A,
                                             const unsigned short* __restrict__ Bp,
                                             const float* __restrict__ b1,
                                             const float* __restrict__ w2,
                                             const float* __restrict__ b2,
                                             float* __restrict__ scores, int M) {
  int l = threadIdx.x & 63;
  int w = threadIdx.x >> 6;
  int mloc = l & 15, q = l >> 4;
  int row0 = blockIdx.x * 128 + w * 32;

  int r0 = row0 + mloc;      if (r0 > M - 1) r0 = M - 1;
  int r1 = row0 + 16 + mloc; if (r1 > M - 1) r1 = M - 1;
  const unsigned short* ap0 = A + (size_t)r0 * 256 + q * 8;
  const unsigned short* ap1 = A + (size_t)r1 * 256 + q * 8;
  const unsigned short* bp = Bp + (size_t)l * 8;

  f32x4 acc[2][8];
#pragma unroll
  for (int rt = 0; rt < 2; ++rt)
#pragma unroll
    for (int ct = 0; ct < 8; ++ct) acc[rt][ct] = (f32x4){0.f, 0.f, 0.f, 0.f};
#pragma unroll
  for (int ks = 0; ks < 8; ++ks) {
    s16x8 a0 = *(const s16x8*)(ap0 + ks * 32);
    s16x8 a1 = *(const s16x8*)(ap1 + ks * 32);
#pragma unroll
    for (int ct = 0; ct < 8; ++ct) {
      s16x8 b = *(const s16x8*)(bp + ks * 4096 + ct * 512);
      acc[0][ct] = __builtin_amdgcn_mfma_f32_16x16x32_bf16(a0, b, acc[0][ct], 0, 0, 0);
      acc[1][ct] = __builtin_amdgcn_mfma_f32_16x16x32_bf16(a1, b, acc[1][ct], 0, 0, 0);
    }
  }
  float bv[8], wv[8];
#pragma unroll
  for (int ct = 0; ct < 8; ++ct) {
    bv[ct] = b1[ct * 16 + mloc];
    wv[ct] = w2[ct * 16 + mloc];
  }
  float b2v = b2[0];
#pragma unroll
  for (int rt = 0; rt < 2; ++rt)
#pragma unroll
    for (int r = 0; r < 4; ++r) {
      float p = 0.0f;
#pragma unroll
      for (int ct = 0; ct < 8; ++ct) p = fmaf(tanhf(acc[rt][ct][r] + bv[ct]), wv[ct], p);
      p += __shfl_xor(p, 1, 64);
      p += __shfl_xor(p, 2, 64);
      p += __shfl_xor(p, 4, 64);
      p += __shfl_xor(p, 8, 64);
      int row = row0 + rt * 16 + q * 4 + r;
      if (mloc == 0 && row < M) scores[row] = p + b2v;
    }
}

// BN partial: block b sums S1/S2 over graphs [b*32,(b+1)*32) — coalesced (thread = column)
__global__ __launch_bounds__(256) void k_bn_part(const float* __restrict__ S1, const float* __restrict__ S2,
                                                 float* __restrict__ P1, float* __restrict__ P2) {
  int b = blockIdx.x, c = threadIdx.x;
  float s1 = 0.0f, s2 = 0.0f;
  for (int g = b * 32; g < b * 32 + 32; ++g) {
    s1 += S1[(size_t)g * 256 + c];
    s2 += S2[(size_t)g * 256 + c];
  }
  P1[(size_t)b * 256 + c] = s1;
  P2[(size_t)b * 256 + c] = s2;
}

// BN finalize: fold 64 partials per column, compute abuf/bbuf (thread = column, no reduce)
__global__ __launch_bounds__(256) void k_bn_fin2(const float* __restrict__ P1, const float* __restrict__ P2,
                                                 const float* __restrict__ gamma, const float* __restrict__ beta,
                                                 float* __restrict__ abuf, float* __restrict__ bbuf, int n) {
  int c = threadIdx.x;
  float s1 = 0.0f, s2 = 0.0f;
  for (int r = 0; r < 64; ++r) {
    s1 += P1[(size_t)r * 256 + c];
    s2 += P2[(size_t)r * 256 + c];
  }
  float inv = 1.0f / (float)n;
  float mu = s1 * inv;
  float var = s2 * inv - mu * mu;
  float rstd = rsqrtf(var + 1e-5f);
  float a = gamma[c] * rstd;
  abuf[c] = a;
  bbuf[c] = beta[c] - mu * a;
}

// per-graph: gmean/rinv from S1/S2 in-block, apply BN+PairNorm+relu; zeroes S1/S2 for next layer.
template <int LAST>
__global__ __launch_bounds__(256) void k_apply(float* __restrict__ z, const float* __restrict__ abuf,
                                               const float* __restrict__ bbuf, const int* __restrict__ gstart,
                                               const int* __restrict__ cnti, const float* __restrict__ cntf,
                                               float* __restrict__ S1, float* __restrict__ S2,
                                               unsigned short* __restrict__ hb) {
  __shared__ float rT[256], rM[256];
  int g = blockIdx.x, c = threadIdx.x;
  float a = abuf[c], b = bbuf[c];
  size_t idx = (size_t)g * 256 + c;
  float s1 = S1[idx];
  float s2 = S2[idx];
  S1[idx] = 0.0f;          // re-zero for next layer's fused stats
  S2[idx] = 0.0f;
  float nr = (float)cnti[g];
  float ic = 1.0f / cntf[g];
  float mean = (a * s1 + nr * b) * ic;
  float term = fmaf(a * a, s2, fmaf(2.0f * a * b, s1, nr * b * b));
  rT[c] = term;
  rM[c] = mean * mean;
  __syncthreads();
  for (int off = 128; off; off >>= 1) {
    if (c < off) { rT[c] += rT[c + off]; rM[c] += rM[c + off]; }
    __syncthreads();
  }
  float cr = nr > 0.0f ? 1.0f : 0.0f;
  float rinv = rsqrtf(1e-5f + rT[0] * ic - cr * rM[0]);
  int r0 = gstart[g], r1 = r0 + cnti[g];
  for (int r = r0; r < r1; ++r) {
    float v = (fmaf(a, z[(size_t)r * 256 + c], b) - mean) * rinv;
    v = v > 0.0f ? v : 0.0f;
    hb[(size_t)r * 256 + c] = f2b(v);
    if (LAST) z[(size_t)r * 256 + c] = v;
  }
}

// per-graph fused pooling + output
__global__ __launch_bounds__(256) void k_poolout(const float* __restrict__ h, const float* __restrict__ scores,
                                                 const int* __restrict__ gstart, const int* __restrict__ cnti,
                                                 const float* __restrict__ cntf, float* __restrict__ out) {
  int g = blockIdx.x, c = threadIdx.x;
  int r0 = gstart[g], r1 = r0 + cnti[g];
  float ma = 0.0f, aa = 0.0f, mx = 0.0f, wa = 0.0f;
  for (int r = r0; r < r1; ++r) {
    float wgt = __expf(scores[r]);
    float hv = h[(size_t)r * 256 + c];
    ma += hv;
    aa = fmaf(hv, wgt, aa);
    mx = fmaxf(mx, hv);
    wa += wgt;
  }
  out[(size_t)g * 768 + c] = ma / cntf[g];
  out[(size_t)g * 768 + 256 + c] = mx;
  out[(size_t)g * 768 + 512 + c] = aa / (wa + 1e-8f);
}

extern "C" void kernel_launch(void* const* d_in, const int* in_sizes, int n_in,
                              void* d_out, int out_size, void* d_ws, size_t ws_size,
                              hipStream_t stream) {
  const float* x         = (const float*)d_in[0];
  const float* edge_attr = (const float*)d_in[1];
  const float* node_w    = (const float*)d_in[2];
  const float* node_b    = (const float*)d_in[3];
  const float* edge_w    = (const float*)d_in[4];
  const float* edge_b    = (const float*)d_in[5];
  const float* conv_w    = (const float*)d_in[6];
  const float* conv_b    = (const float*)d_in[7];
  const float* mlp_w1    = (const float*)d_in[8];
  const float* mlp_b1    = (const float*)d_in[9];
  const float* mlp_w2    = (const float*)d_in[10];
  const float* mlp_b2    = (const float*)d_in[11];
  const float* eps       = (const float*)d_in[12];
  const float* bn_gamma  = (const float*)d_in[13];
  const float* bn_beta   = (const float*)d_in[14];
  const float* att_w1    = (const float*)d_in[15];
  const float* att_b1    = (const float*)d_in[16];
  const float* att_w2    = (const float*)d_in[17];
  const float* att_b2    = (const float*)d_in[18];
  const int*   eidx      = (const int*)d_in[19];
  const int*   batch     = (const int*)d_in[20];
  float* out = (float*)d_out;
  float* ws  = (float*)d_ws;

  float*          zbuf = ws + O_Z;
  unsigned short* zb   = (unsigned short*)(ws + O_ZB);
  unsigned short* hb   = (unsigned short*)(ws + O_HB);
  float* S1    = ws + O_S1;
  float* S2    = ws + O_S2;
  float* abuf  = ws + O_ABUF;
  float* bbuf  = ws + O_BBUF;
  int*   cnti  = (int*)(ws + O_CNTI);
  float* cntf  = ws + O_CNTF;
  float* scor  = ws + O_SCOR;
  int*   curs  = (int*)(ws + O_SCOR);
  float* weff  = ws + O_WEFF;
  float* beff  = ws + O_BEFF;
  int*   deg   = (int*)(ws + O_DEG);
  int*   strt  = (int*)(ws + O_STRT);
  int*   bsum  = (int*)(ws + O_BSUM);
  uint4* csr   = (uint4*)(ws + O_CSR);
  unsigned short* w1p = (unsigned short*)(ws + O_W1P);
  unsigned short* w2p = (unsigned short*)(ws + O_W2P);
  unsigned short* atp = (unsigned short*)(ws + O_ATP);
  int*   gst   = (int*)(ws + O_GST);
  unsigned short* nwp = (unsigned short*)(ws + O_NWP);
  float* bnp1  = ws + O_BNP;
  float* bnp2  = ws + O_BNP + 16384;
  const int* esrc = eidx;
  const int* edst = eidx + EE;

  // graph counts + offsets
  k_zero<<<8, 256, 0, stream>>>((float*)cnti, GG);
  k_count<<<(NN + 255) / 256, 256, 0, stream>>>(batch, cnti, NN);
  k_gscan<<<1, 256, 0, stream>>>(cnti, gst, cntf);

  // fused edge weights + weight packing + MFMA node embedding
  k_wfuse<<<LL, 256, 0, stream>>>(edge_w, edge_b, conv_w, conv_b, weff, beff);
  k_pack_all<<<528, 256, 0, stream>>>(mlp_w1, mlp_w2, att_w1, w1p, w2p, atp);
  k_pack_node<<<12, 256, 0, stream>>>(node_w, nwp);
  k_embed_mfma<<<(NN + 63) / 64, 256, 0, stream>>>(x, nwp, node_b, hb, NN);

  // S1/S2 zero for layer-0 fused stats (subsequent layers re-zeroed by k_apply)
  k_zero<<<1024, 256, 0, stream>>>(S1, 2 * 524288);

  // CSR build (by dst)
  const int nscan = (NN + 255) / 256;  // 391
  k_zero<<<256, 256, 0, stream>>>((float*)deg, NN);
  k_deg<<<(EE + 255) / 256, 256, 0, stream>>>(edst, deg, EE);
  k_scan_part<<<nscan, 256, 0, stream>>>(deg, strt, bsum, NN);
  k_scan_top<<<1, 512, 0, stream>>>(bsum, nscan);
  k_scan_add<<<nscan, 256, 0, stream>>>(strt, bsum, curs, NN);
  k_fill<<<(EE + 255) / 256, 256, 0, stream>>>(edge_attr, esrc, edst, curs, csr, EE);

  const int mtiles64  = (NN + 63) / 64;    // 1563
  const int mtiles128 = (NN + 127) / 128;  // 782

  for (int i = 0; i < LL; ++i) {
    k_edge_csr<<<NN / 16, 256, 0, stream>>>(csr, strt, deg, weff + (size_t)i * 1536,
                                            beff + (size_t)i * 256, hb, zb, eps, i, NN);
    k_mlp<<<mtiles64, 256, 0, stream>>>(zb, w1p + (size_t)i * 65536, mlp_b1 + (size_t)i * 256,
                                        w2p + (size_t)i * 65536, mlp_b2 + (size_t)i * 256, zbuf,
                                        batch, S1, S2, NN);
    k_bn_part<<<64, 256, 0, stream>>>(S1, S2, bnp1, bnp2);
    k_bn_fin2<<<1, 256, 0, stream>>>(bnp1, bnp2, bn_gamma + (size_t)i * 256,
                                     bn_beta + (size_t)i * 256, abuf, bbuf, NN);
    if (i == LL - 1)
      k_apply<1><<<GG, 256, 0, stream>>>(zbuf, abuf, bbuf, gst, cnti, cntf, S1, S2, hb);
    else
      k_apply<0><<<GG, 256, 0, stream>>>(zbuf, abuf, bbuf, gst, cnti, cntf, S1, S2, hb);
  }

  // pooling (zbuf holds fp32 h)
  k_att<<<mtiles128, 256, 0, stream>>>(hb, atp, att_b1, att_w2, att_b2, scor, NN);
  k_poolout<<<GG, 256, 0, stream>>>(zbuf, scor, gst, cnti, cntf, out);
}